// Round 5
// baseline (355.579 us; speedup 1.0000x reference)
//
#include <hip/hip_runtime.h>
#include <math.h>

#define NN 100000
#define NE 800000
#define C1 256   // HEADS*HID
#define OC 40
#define XPAD 64  // padded xp2 row stride (fp16) = 128 B = 1 cacheline
#define NEG 0.2f
#define FCHUNK 4096
#define G1BLK 1563   // gemm1 compute blocks; blocks beyond run deg_count

typedef _Float16 h4 __attribute__((ext_vector_type(4)));
typedef _Float16 h8 __attribute__((ext_vector_type(8)));
typedef float f4v __attribute__((ext_vector_type(4)));
typedef float f2v __attribute__((ext_vector_type(2)));

static __device__ __forceinline__ float leaky(float v){ return v > 0.f ? v : NEG*v; }

static __device__ __forceinline__ h8 mk8(float4 a, float4 b){
  h8 r = {(_Float16)a.x,(_Float16)a.y,(_Float16)a.z,(_Float16)a.w,
          (_Float16)b.x,(_Float16)b.y,(_Float16)b.z,(_Float16)b.w};
  return r;
}

// Permuted xp1/h1 row layout: storage element e = 4*l + j (l = dword/lane 0..63, j = byte 0..3)
// holds logical col pcol(l,j) = (l>>5)*128 + ((l>>4)&1)*64 + 16*j + (l&15).

// ---------------- W1t/W2t transforms + deg init (fused: blocks 194.. init deg) ----------------
__global__ __launch_bounds__(256) void k_wt(const float* __restrict__ W1, const float* __restrict__ W2,
                                            const float* __restrict__ aS1, const float* __restrict__ aD1,
                                            const float* __restrict__ aS2, const float* __restrict__ aD2,
                                            _Float16* __restrict__ W1t, _Float16* __restrict__ W2t,
                                            int* __restrict__ deg){
  int b = blockIdx.x;
  if (b < 128){
    int k = b, nb = threadIdx.x;
    W1t[(size_t)nb*128 + k] = (_Float16)W1[k*256 + nb];
  } else if (b < 176){
    int nb = b - 128;            // 0..47 (pad 40->48 with zeros)
    int e = threadIdx.x;         // storage index 0..255
    int l = e >> 2, j = e & 3;
    int k = (l>>5)*128 + ((l>>4)&1)*64 + j*16 + (l&15);   // logical k of storage slot e
    float v = (nb < OC) ? W2[(size_t)k*OC + nb] : 0.f;
    W2t[(size_t)nb*256 + e] = (_Float16)v;
  } else if (b < 178){
    int b2 = b - 176;            // 0 = src heads, 1 = dst heads
    int h  = threadIdx.x >> 5;   // 0..7
    int kb = (threadIdx.x & 31) * 4;
    const float* att = b2 ? aD1 : aS1;
    #pragma unroll
    for (int kk = 0; kk < 4; ++kk){
      int k = kb + kk;
      float s = 0.f;
      for (int c = 0; c < 32; ++c) s += W1[k*256 + h*32 + c] * att[h*32 + c];
      W1t[(size_t)(256 + b2*8 + h)*128 + k] = (_Float16)s;
    }
  } else if (b < 194){
    int j = b - 178;             // 0..15 -> W2t col 48+j (j=0 src dot, j=1 dst dot, rest zero)
    int e = threadIdx.x;
    int l = e >> 2, jj = e & 3;
    int k = (l>>5)*128 + ((l>>4)&1)*64 + jj*16 + (l&15);
    float v = 0.f;
    if (j == 0){ for (int c = 0; c < OC; ++c) v += W2[(size_t)k*OC + c] * aS2[c]; }
    else if (j == 1){ for (int c = 0; c < OC; ++c) v += W2[(size_t)k*OC + c] * aD2[c]; }
    W2t[(size_t)(48 + j)*256 + e] = (_Float16)v;
  } else {
    int i = (b - 194)*256 + threadIdx.x;
    if (i < NN) deg[i] = 1;      // self-loop slot reserved
  }
}

// ---------------- K1: xp1 = x @ W1 via fp16 MFMA + fused deg_count (blocks >= G1BLK) ----------------
// One wave per 16 rows x ALL 272 cols: no LDS, no syncthreads, x read exactly once,
// acc = 17 f4v (68 VGPR). All 8 A-loads (dwordx4) issued up front for MLP; W1t (70 KB) is L1/L2-hot.
__global__ __launch_bounds__(256) void k_gemm1(const float* __restrict__ x,
    const _Float16* __restrict__ W1t, unsigned* __restrict__ xp1w,
    float* __restrict__ asrc, float* __restrict__ adst,
    const int* __restrict__ ei, int* __restrict__ deg)
{
  if (blockIdx.x >= G1BLK){
    // deg_count rides in gemm1's latency bubbles (independent work, co-scheduled)
    int i = (blockIdx.x - G1BLK)*256 + threadIdx.x;
    if (i < NE) atomicAdd(&deg[ei[NE + i]], 1);
    return;
  }
  const int tid  = threadIdx.x;
  const int lane = tid & 63;
  const int w    = tid >> 6;
  const int n = lane & 15, quad = lane >> 4;
  const int r0 = blockIdx.x * 64 + w*16;

  int ra = r0 + n; ra = ra < NN ? ra : NN-1;
  const float* xr = x + (size_t)ra*128 + quad*8;

  // phase 1: issue all 8 A-loads (covers K=128 for this wave's 16 rows)
  float4 fa[4][2];
  #pragma unroll
  for (int ks = 0; ks < 4; ++ks){
    fa[ks][0] = *(const float4*)(xr + ks*32);
    fa[ks][1] = *(const float4*)(xr + ks*32 + 4);
  }

  f4v acc[17];
  #pragma unroll
  for (int ct = 0; ct < 17; ++ct) acc[ct] = (f4v){0.f,0.f,0.f,0.f};

  #pragma unroll
  for (int ks = 0; ks < 4; ++ks){
    h8 a = mk8(fa[ks][0], fa[ks][1]);
    #pragma unroll
    for (int ct = 0; ct < 17; ++ct){
      const int col = (ct < 16) ? (ct*16 + n) : (256 + n);   // ct=16: attention-dot cols
      h8 b = *(const h8*)(W1t + (size_t)col*128 + ks*32 + quad*8);
      acc[ct] = __builtin_amdgcn_mfma_f32_16x16x32_f16(a, b, acc[ct], 0, 0, 0);
    }
  }

  #pragma unroll
  for (int reg = 0; reg < 4; ++reg){
    const int row = r0 + quad*4 + reg;
    if (row < NN){
      float v[16];
      #pragma unroll
      for (int ct = 0; ct < 16; ++ct) v[ct] = acc[ct][reg];
      // pack to permuted fp8 storage: dword l = 16*q' + n segment mapping (see pcol comment)
      unsigned dw0 = (unsigned)__builtin_amdgcn_cvt_pk_fp8_f32(v[0], v[1], 0, false);
      dw0 = (unsigned)__builtin_amdgcn_cvt_pk_fp8_f32(v[2], v[3], (int)dw0, true);
      unsigned dw1 = (unsigned)__builtin_amdgcn_cvt_pk_fp8_f32(v[4], v[5], 0, false);
      dw1 = (unsigned)__builtin_amdgcn_cvt_pk_fp8_f32(v[6], v[7], (int)dw1, true);
      unsigned dw2 = (unsigned)__builtin_amdgcn_cvt_pk_fp8_f32(v[8], v[9], 0, false);
      dw2 = (unsigned)__builtin_amdgcn_cvt_pk_fp8_f32(v[10], v[11], (int)dw2, true);
      unsigned dw3 = (unsigned)__builtin_amdgcn_cvt_pk_fp8_f32(v[12], v[13], 0, false);
      dw3 = (unsigned)__builtin_amdgcn_cvt_pk_fp8_f32(v[14], v[15], (int)dw3, true);
      unsigned* xw = xp1w + (size_t)row*64;
      xw[n]      = dw0;
      xw[16 + n] = dw1;
      xw[32 + n] = dw2;
      xw[48 + n] = dw3;
      float vE = acc[16][reg];
      if (n < 8) asrc[row*8 + n] = vE;
      else       adst[row*8 + (n - 8)] = vE;
    }
  }
}

// ---------------- CSR build (dst-sorted) ----------------
__global__ __launch_bounds__(256) void k_scan1(const int* __restrict__ deg, int* part, int* bsum){
  __shared__ int lds[256];
  const int t = threadIdx.x;
  const int base = blockIdx.x*1024;
  int v[4]; int s = 0;
  #pragma unroll
  for (int i = 0; i < 4; ++i){ int idx = base + t*4 + i; v[i] = (idx < NN) ? deg[idx] : 0; s += v[i]; }
  lds[t] = s; __syncthreads();
  for (int off = 1; off < 256; off <<= 1){
    int xx = (t >= off) ? lds[t-off] : 0;
    __syncthreads();
    lds[t] += xx;
    __syncthreads();
  }
  int excl = lds[t] - s;
  #pragma unroll
  for (int i = 0; i < 4; ++i){ int idx = base + t*4 + i; if (idx < NN) part[idx] = excl; excl += v[i]; }
  if (t == 255) bsum[blockIdx.x] = lds[255];
}
__global__ void k_scan2(const int* __restrict__ bsum, int* boff){
  const int l = threadIdx.x;   // 64 threads, lane i handles elements i and 64+i
  int a = (l      < 98) ? bsum[l]      : 0;
  int b = (64 + l < 98) ? bsum[64 + l] : 0;
  int sa = a, sb = b;
  #pragma unroll
  for (int off = 1; off < 64; off <<= 1){
    int ta = __shfl_up(sa, off, 64);
    int tb = __shfl_up(sb, off, 64);
    if (l >= off){ sa += ta; sb += tb; }
  }
  const int totalA = __shfl(sa, 63, 64);
  if (l      < 98) boff[l]      = sa - a;
  if (64 + l < 98) boff[64 + l] = totalA + sb - b;
}
__global__ __launch_bounds__(256) void k_scan3(const int* __restrict__ part, const int* __restrict__ boff,
                                               int* rowptr, int* cursor){
  int i = blockIdx.x*256 + threadIdx.x;
  if (i < NN){ int v = part[i] + boff[i >> 10]; rowptr[i] = v; cursor[i] = v; }
  if (i == 0) rowptr[NN] = NN + NE;
}
// XCD-partitioned fill: blocks dispatch round-robin over the 8 XCDs (bid&7); each esrc/cursor
// line is written by exactly one XCD's L2 (kills partial-line HBM write amplification).
__global__ __launch_bounds__(256) void k_fill(const int* __restrict__ ei, int* cursor, int* __restrict__ esrc){
  const int xcd = blockIdx.x & 7;
  const int base = (blockIdx.x >> 3) * FCHUNK;
  const int lo = xcd * (NN/8), hi = lo + (NN/8);
  const int end = (base + FCHUNK < NE + NN) ? (base + FCHUNK) : (NE + NN);
  for (int i = base + threadIdx.x; i < end; i += 256){
    int s, d;
    if (i < NE){ s = ei[i]; d = ei[NE + i]; } else { s = d = i - NE; }
    if (d >= lo && d < hi){
      int slot = atomicAdd(&cursor[d], 1);
      esrc[slot] = s;
    }
  }
}

// ---------------- K3: layer-1 aggregation ----------------
// Slot-major p layout: lane holds p for slot (lane&15) at heads hA=(lane>>4)*2 (pv0) and hA+1 (pv1).
template<int B>
static __device__ __forceinline__ void agg1_batch(
    const int j0, const int je, const int lane,
    const int* __restrict__ esrc, const float* __restrict__ asrc,
    const float adA, const float adB,
    const unsigned* __restrict__ xp1w,
    f2v& accLo, f2v& accHi, float& z0, float& z1)
{
  const int cnt = je - j0;                 // wave-uniform
  const int slot = lane & 15;
  const int hA = (lane >> 4) << 1;
  int idx = j0 + slot; idx = idx < je ? idx : je - 1;   // clamped, always valid
  const int sv = esrc[idx];                // lanes 0..15 hold slots 0..15
  float pv0 = 0.f, pv1 = 0.f;
  if (slot < cnt){
    f2v av = *(const f2v*)(asrc + (size_t)sv*8 + hA);
    pv0 = __expf(leaky(av.x + adA));
    pv1 = __expf(leaky(av.y + adB));
  }
  z0 += pv0; z1 += pv1;
  // phase 1: B unconditional row loads from clamped SGPR bases (padded slots repeat last row -> L1)
  unsigned u[B];
  #pragma unroll
  for (int e = 0; e < B; ++e){
    int s = __builtin_amdgcn_readlane(sv, e);
    u[e] = xp1w[(size_t)s*64 + lane];
  }
  __builtin_amdgcn_sched_barrier(0);   // pin: all loads issued before any FMA below
  // phase 2: decode + fma (p = 0 for padded slots -> garbage-free)
  const int pb = lane & 48;
  #pragma unroll
  for (int e = 0; e < B; ++e){
    const float pA = __shfl(pv0, pb | e, 64);
    const float pB = __shfl(pv1, pb | e, 64);
    f2v lo = __builtin_amdgcn_cvt_pk_f32_fp8((int)u[e], false);
    f2v hi = __builtin_amdgcn_cvt_pk_f32_fp8((int)u[e], true);
    accLo += (f2v){pA, pA} * lo;
    accHi += (f2v){pB, pB} * hi;
  }
}

__global__ __launch_bounds__(256) void k_agg1(const unsigned* __restrict__ xp1w,
    const float* __restrict__ asrc, const float* __restrict__ adst,
    const float* __restrict__ b1, const int* __restrict__ rowptr,
    const int* __restrict__ esrc, _Float16* __restrict__ h1)
{
  const int lane = threadIdx.x & 63;
  int n = __builtin_amdgcn_readfirstlane(blockIdx.x*4 + (threadIdx.x >> 6));
  const int hA = (lane >> 4) << 1;
  const f2v ad = *(const f2v*)(adst + (size_t)n*8 + hA);   // both heads' dst terms
  const int jb = rowptr[n], je = rowptr[n+1];
  const int cbase = (lane>>5)*128 + ((lane>>4)&1)*64 + (lane&15);
  const float bp0 = b1[cbase], bp1 = b1[cbase+16], bp2 = b1[cbase+32], bp3 = b1[cbase+48];
  f2v accLo = {0.f,0.f}, accHi = {0.f,0.f};
  float z0 = 0.f, z1 = 0.f;

  int j0 = jb;
  while (j0 < je){
    if (je - j0 > 8){
      agg1_batch<16>(j0, je, lane, esrc, asrc, ad.x, ad.y, xp1w, accLo, accHi, z0, z1);
      j0 += 16;
    } else {
      agg1_batch<8>(j0, je, lane, esrc, asrc, ad.x, ad.y, xp1w, accLo, accHi, z0, z1);
      j0 += 8;
    }
  }
  #pragma unroll
  for (int off = 1; off <= 8; off <<= 1){
    z0 += __shfl_xor(z0, off, 64);
    z1 += __shfl_xor(z1, off, 64);
  }
  const float invA = 1.f/(z0 + 1e-16f), invB = 1.f/(z1 + 1e-16f);
  h4 o = {(_Float16)fmaxf(accLo.x*invA + bp0, 0.f),
          (_Float16)fmaxf(accLo.y*invA + bp1, 0.f),
          (_Float16)fmaxf(accHi.x*invB + bp2, 0.f),
          (_Float16)fmaxf(accHi.y*invB + bp3, 0.f)};
  ((h4*)h1)[(size_t)n*64 + lane] = o;   // h1 inherits the permuted col order
}

// ---------------- K4: xp2 = h1 @ W2 via fp16 MFMA; attention dots via extra col tile ----------------
__global__ __launch_bounds__(256) void k_gemm2(const _Float16* __restrict__ h1,
    const _Float16* __restrict__ W2t, _Float16* __restrict__ xp2,
    float* __restrict__ asrc2, float* __restrict__ adst2)
{
  const int tid  = threadIdx.x;
  const int lane = tid & 63;
  const int w    = tid >> 6;
  const int n = lane & 15, quad = lane >> 4;
  const int r0 = blockIdx.x * 64 + w*16;

  f4v acc[4];
  #pragma unroll
  for (int ct = 0; ct < 4; ++ct) acc[ct] = (f4v){0.f,0.f,0.f,0.f};

  int rr = r0 + n; rr = rr < NN ? rr : NN-1;

  #pragma unroll
  for (int ks = 0; ks < 8; ++ks){
    h8 a = *(const h8*)(h1 + (size_t)rr*256 + ks*32 + quad*8);
    #pragma unroll
    for (int ct = 0; ct < 4; ++ct){
      h8 b = *(const h8*)(W2t + (size_t)(ct*16 + n)*256 + ks*32 + quad*8);
      acc[ct] = __builtin_amdgcn_mfma_f32_16x16x32_f16(a, b, acc[ct], 0, 0, 0);
    }
  }

  #pragma unroll
  for (int reg = 0; reg < 4; ++reg){
    const int row = r0 + quad*4 + reg;
    if (row < NN){
      float v0 = acc[0][reg], v1 = acc[1][reg], v2 = acc[2][reg], v3 = acc[3][reg];
      _Float16* xr = xp2 + (size_t)row*XPAD + n;
      xr[0]  = (_Float16)v0;
      xr[16] = (_Float16)v1;
      if (n < 8) xr[32] = (_Float16)v2;
      if (n == 0) asrc2[row] = v3;
      if (n == 1) adst2[row] = v3;
    }
  }
}

// ---------------- K5: layer-2 aggregation, 4 edges/wave (16-lane groups), b64 row loads ----------------
__global__ __launch_bounds__(256) void k_agg2(const _Float16* __restrict__ xp2,
    const float* __restrict__ asrc2, const float* __restrict__ adst2,
    const float* __restrict__ b2, const int* __restrict__ rowptr,
    const int* __restrict__ esrc, float* __restrict__ out)
{
  const int lane = threadIdx.x & 63;
  const int g = lane >> 4;          // edge sub-group 0..3
  const int t = lane & 15;          // channel quad: channels 4t..4t+3
  int n = __builtin_amdgcn_readfirstlane(blockIdx.x*4 + (threadIdx.x >> 6));
  const float ad = adst2[n];
  const int jb = rowptr[n], je = rowptr[n+1];
  f4v acc = {0.f,0.f,0.f,0.f};
  float zacc = 0.f;

  for (int j0 = jb; j0 < je; j0 += 16){
    const int cnt = je - j0;        // wave-uniform
    int idx = j0 + t; idx = idx < je ? idx : je - 1;   // clamped, always valid
    const int sv = esrc[idx];       // slot t (replicated across the 4 groups)
    const float pv = (t < cnt) ? __expf(leaky(asrc2[sv] + ad)) : 0.f;
    zacc += pv;
    // phase 1: 4 b64 loads, each covering 4 edges (one per group)
    h4 u[4];
    #pragma unroll
    for (int e4 = 0; e4 < 4; ++e4){
      int svg = __shfl(sv, e4*4 + g, 64);
      u[e4] = *(const h4*)(xp2 + (size_t)svg*XPAD + t*4);
    }
    __builtin_amdgcn_sched_barrier(0);   // pin: loads before FMA chain
    // phase 2: p broadcast + fma (p = 0 for padded slots -> garbage-free)
    #pragma unroll
    for (int e4 = 0; e4 < 4; ++e4){
      const float p = __shfl(pv, e4*4 + g, 64);
      acc.x += p*(float)u[e4].x;
      acc.y += p*(float)u[e4].y;
      acc.z += p*(float)u[e4].z;
      acc.w += p*(float)u[e4].w;
    }
  }
  // z over slots (groups identical)
  #pragma unroll
  for (int off = 1; off <= 8; off <<= 1) zacc += __shfl_xor(zacc, off, 64);
  // acc over the 4 edge groups (same channel quad t mixes only with itself)
  #pragma unroll
  for (int off = 16; off <= 32; off <<= 1){
    acc.x += __shfl_xor(acc.x, off, 64);
    acc.y += __shfl_xor(acc.y, off, 64);
    acc.z += __shfl_xor(acc.z, off, 64);
    acc.w += __shfl_xor(acc.w, off, 64);
  }
  const float inv = 1.f/(zacc + 1e-16f);
  const bool act = t < 10;          // 4t < OC=40
  float4 bv = act ? *(const float4*)(b2 + 4*t) : make_float4(0.f,0.f,0.f,0.f);
  float v0 = acc.x*inv + bv.x, v1 = acc.y*inv + bv.y;
  float v2 = acc.z*inv + bv.z, v3 = acc.w*inv + bv.w;
  float m = act ? fmaxf(fmaxf(v0,v1), fmaxf(v2,v3)) : -INFINITY;
  #pragma unroll
  for (int off = 1; off <= 8; off <<= 1) m = fmaxf(m, __shfl_xor(m, off, 64));
  float es = act ? (__expf(v0-m)+__expf(v1-m)+__expf(v2-m)+__expf(v3-m)) : 0.f;
  #pragma unroll
  for (int off = 1; off <= 8; off <<= 1) es += __shfl_xor(es, off, 64);
  if (lane < 10){                   // group 0, t<10: coalesced float4 stores
    float lse = m + __logf(es);
    float4 o = make_float4(v0-lse, v1-lse, v2-lse, v3-lse);
    *(float4*)(out + (size_t)n*OC + 4*t) = o;
  }
}

extern "C" void kernel_launch(void* const* d_in, const int* in_sizes, int n_in,
                              void* d_out, int out_size, void* d_ws, size_t ws_size,
                              hipStream_t stream)
{
  const float* x   = (const float*)d_in[0];
  const int*   ei  = (const int*)  d_in[1];
  const float* W1  = (const float*)d_in[2];
  const float* aS1 = (const float*)d_in[3];
  const float* aD1 = (const float*)d_in[4];
  const float* b1  = (const float*)d_in[5];
  const float* W2  = (const float*)d_in[6];
  const float* aS2 = (const float*)d_in[7];
  const float* aD2 = (const float*)d_in[8];
  const float* b2  = (const float*)d_in[9];
  float* out = (float*)d_out;

  char* wsp = (char*)d_ws;
  size_t off = 0;
  auto alloc = [&](size_t bytes){ void* p = wsp + off; off += (bytes + 255) & ~(size_t)255; return p; };
  unsigned* xp1w = (unsigned*)alloc((size_t)NN*C1);            // fp8, permuted, 64 dwords/row
  _Float16* h1  = (_Float16*)alloc((size_t)NN*C1*2);           // fp16, permuted cols
  float* as1  = (float*)alloc((size_t)NN*8*4);
  float* ad1  = (float*)alloc((size_t)NN*8*4);
  float* as2  = (float*)alloc((size_t)NN*4);
  float* ad2  = (float*)alloc((size_t)NN*4);
  int* deg    = (int*)alloc((size_t)NN*4);
  int* part   = (int*)alloc((size_t)NN*4);
  int* rowptr = (int*)alloc((size_t)(NN+1)*4);
  int* cursor = (int*)alloc((size_t)NN*4);
  int* bsum   = (int*)alloc(98*4);
  int* boff   = (int*)alloc(98*4);
  int* esrc   = (int*)alloc((size_t)(NN+NE)*4);
  _Float16* W1t = (_Float16*)alloc((size_t)272*128*2);   // 256 cols + 16 attention-dot cols
  _Float16* W2t = (_Float16*)alloc((size_t)64*256*2);    // 48 cols + 16 (2 dot cols + zero pad)
  _Float16* xp2 = (_Float16*)alloc((size_t)NN*XPAD*2);   // 12.8 MB, 128B-aligned rows
  (void)ws_size; (void)in_sizes; (void)n_in; (void)out_size;

  const int fill_chunks = (NE + NN + FCHUNK - 1) / FCHUNK;   // 220
  const int deg_blocks  = (NE + 255) / 256;                  // 3125

  k_wt    <<<194 + (NN + 255)/256, 256, 0, stream>>>(W1, W2, aS1, aD1, aS2, aD2, W1t, W2t, deg);
  k_gemm1 <<<G1BLK + deg_blocks,   256, 0, stream>>>(x, W1t, xp1w, as1, ad1, ei, deg);
  k_scan1 <<<98,   256, 0, stream>>>(deg, part, bsum);
  k_scan2 <<<1,    64,  0, stream>>>(bsum, boff);
  k_scan3 <<<391,  256, 0, stream>>>(part, boff, rowptr, cursor);
  k_fill  <<<fill_chunks*8, 256, 0, stream>>>(ei, cursor, esrc);
  k_agg1  <<<25000,256, 0, stream>>>(xp1w, as1, ad1, b1, rowptr, esrc, h1);
  k_gemm2 <<<1563, 256, 0, stream>>>(h1, W2t, xp2, as2, ad2);
  k_agg2  <<<25000,256, 0, stream>>>(xp2, as2, ad2, b2, rowptr, esrc, out);
}

// Round 6
// 322.739 us; speedup vs baseline: 1.1018x; 1.1018x over previous
//
#include <hip/hip_runtime.h>
#include <math.h>

#define NN 100000
#define NE 800000
#define C1 256   // HEADS*HID
#define OC 40
#define XPAD 64  // padded xp2 row stride (fp16) = 128 B = 1 cacheline
#define NEG 0.2f
#define FCHUNK 4096
#define G1BLK 782    // gemm1 compute blocks (512 thr, 128 rows); blocks beyond run deg_count

typedef _Float16 h4 __attribute__((ext_vector_type(4)));
typedef _Float16 h8 __attribute__((ext_vector_type(8)));
typedef float f4v __attribute__((ext_vector_type(4)));
typedef float f2v __attribute__((ext_vector_type(2)));

static __device__ __forceinline__ float leaky(float v){ return v > 0.f ? v : NEG*v; }

static __device__ __forceinline__ h8 mk8(float4 a, float4 b){
  h8 r = {(_Float16)a.x,(_Float16)a.y,(_Float16)a.z,(_Float16)a.w,
          (_Float16)b.x,(_Float16)b.y,(_Float16)b.z,(_Float16)b.w};
  return r;
}

static __device__ __forceinline__ void gload_lds16h(const _Float16* g, _Float16* l){
  __builtin_amdgcn_global_load_lds((const __attribute__((address_space(1))) void*)g,
                                   (__attribute__((address_space(3))) void*)l, 16, 0, 0);
}

// Permuted xp1/h1 row layout: storage element e = 4*l + j (l = dword/lane 0..63, j = byte 0..3)
// holds logical col pcol(l,j) = (l>>5)*128 + ((l>>4)&1)*64 + 16*j + (l&15).
//
// W1s layout (swizzled B panel, 272 cols x 128 k, fp16): col c's 256B row is split into 16
// segments of 16B (segment s = k>>3); segment s is STORED at slot s^(c&15). gemm1 stages this
// linearly into LDS (global_load_lds can't scatter) and applies the same XOR on ds_read ->
// bank-conflict-free b128 reads (rule: swizzle both sides or neither).

// ---------------- W1s/W2t transforms + deg init (fused: blocks 194.. init deg) ----------------
__global__ __launch_bounds__(256) void k_wt(const float* __restrict__ W1, const float* __restrict__ W2,
                                            const float* __restrict__ aS1, const float* __restrict__ aD1,
                                            const float* __restrict__ aS2, const float* __restrict__ aD2,
                                            _Float16* __restrict__ W1s, _Float16* __restrict__ W2t,
                                            int* __restrict__ deg){
  int b = blockIdx.x;
  if (b < 128){
    int k = b, c = threadIdx.x;
    W1s[(size_t)c*128 + (((k>>3) ^ (c&15))<<3) + (k&7)] = (_Float16)W1[k*256 + c];
  } else if (b < 176){
    int nb = b - 128;            // 0..47 (pad 40->48 with zeros)
    int e = threadIdx.x;         // storage index 0..255
    int l = e >> 2, j = e & 3;
    int k = (l>>5)*128 + ((l>>4)&1)*64 + j*16 + (l&15);   // logical k of storage slot e
    float v = (nb < OC) ? W2[(size_t)k*OC + nb] : 0.f;
    W2t[(size_t)nb*256 + e] = (_Float16)v;
  } else if (b < 178){
    int b2 = b - 176;            // 0 = src heads, 1 = dst heads
    int h  = threadIdx.x >> 5;   // 0..7
    int kb = (threadIdx.x & 31) * 4;
    const float* att = b2 ? aD1 : aS1;
    const int c = 256 + b2*8 + h;
    #pragma unroll
    for (int kk = 0; kk < 4; ++kk){
      int k = kb + kk;
      float s = 0.f;
      for (int cc = 0; cc < 32; ++cc) s += W1[k*256 + h*32 + cc] * att[h*32 + cc];
      W1s[(size_t)c*128 + (((k>>3) ^ (c&15))<<3) + (k&7)] = (_Float16)s;
    }
  } else if (b < 194){
    int j = b - 178;             // 0..15 -> W2t col 48+j (j=0 src dot, j=1 dst dot, rest zero)
    int e = threadIdx.x;
    int l = e >> 2, jj = e & 3;
    int k = (l>>5)*128 + ((l>>4)&1)*64 + jj*16 + (l&15);
    float v = 0.f;
    if (j == 0){ for (int c = 0; c < OC; ++c) v += W2[(size_t)k*OC + c] * aS2[c]; }
    else if (j == 1){ for (int c = 0; c < OC; ++c) v += W2[(size_t)k*OC + c] * aD2[c]; }
    W2t[(size_t)(48 + j)*256 + e] = (_Float16)v;
  } else {
    int i = (b - 194)*256 + threadIdx.x;
    if (i < NN) deg[i] = 1;      // self-loop slot reserved
  }
}

// ---------------- K1: xp1 = x @ W1 via fp16 MFMA, full B panel in LDS ----------------
// 512 thr / 8 waves / 128 rows per block. B = 69,632B LDS (2 blocks/CU = 16 waves/CU).
// Each wave: 8 up-front A-loads (HBM/L3) + 68 swizzled ds_read_b128 + 68 MFMA. No global B chain.
__global__ __launch_bounds__(512, 4) void k_gemm1(const float* __restrict__ x,
    const _Float16* __restrict__ W1s, unsigned* __restrict__ xp1w,
    float* __restrict__ asrc, float* __restrict__ adst,
    const int* __restrict__ ei, int* __restrict__ deg)
{
  __shared__ _Float16 bs[272*128];   // 69,632 B swizzled B panel
  if (blockIdx.x >= G1BLK){
    // deg_count rides in gemm1's latency bubbles (independent work, co-scheduled)
    int i = (blockIdx.x - G1BLK)*512 + threadIdx.x;
    if (i < NE) atomicAdd(&deg[ei[NE + i]], 1);
    return;
  }
  const int tid  = threadIdx.x;
  const int lane = tid & 63;
  const int w    = tid >> 6;          // 0..7
  const int n = lane & 15, quad = lane >> 4;
  const int r0 = blockIdx.x * 128 + w*16;

  // stage the whole swizzled panel linearly: 4352 x 16B segments
  #pragma unroll
  for (int it = 0; it < 8; ++it){
    int idx = it*512 + tid;
    gload_lds16h(W1s + (size_t)idx*8, bs + (size_t)(it*512 + w*64)*8);
  }
  if (w < 4){
    int idx = 4096 + w*64 + lane;
    gload_lds16h(W1s + (size_t)idx*8, bs + (size_t)(4096 + w*64)*8);
  }

  // issue all 8 A-loads up front (K=128 for this wave's 16 rows)
  int ra = r0 + n; ra = ra < NN ? ra : NN-1;
  const float* xr = x + (size_t)ra*128 + quad*8;
  float4 fa[4][2];
  #pragma unroll
  for (int ks = 0; ks < 4; ++ks){
    fa[ks][0] = *(const float4*)(xr + ks*32);
    fa[ks][1] = *(const float4*)(xr + ks*32 + 4);
  }

  __syncthreads();   // drains vmcnt (global_load_lds + A loads)

  f4v acc[17];
  #pragma unroll
  for (int ct = 0; ct < 17; ++ct) acc[ct] = (f4v){0.f,0.f,0.f,0.f};

  #pragma unroll
  for (int ks = 0; ks < 4; ++ks){
    h8 a = mk8(fa[ks][0], fa[ks][1]);
    #pragma unroll
    for (int ct = 0; ct < 17; ++ct){
      const int col = ct*16 + n;                     // ct=16 -> attention-dot cols 256+n
      h8 b = *((const h8*)bs + (size_t)col*16 + (((ks*4 + quad) ^ n)));
      acc[ct] = __builtin_amdgcn_mfma_f32_16x16x32_f16(a, b, acc[ct], 0, 0, 0);
    }
  }

  #pragma unroll
  for (int reg = 0; reg < 4; ++reg){
    const int row = r0 + quad*4 + reg;
    if (row < NN){
      float v[16];
      #pragma unroll
      for (int ct = 0; ct < 16; ++ct) v[ct] = acc[ct][reg];
      unsigned dw0 = (unsigned)__builtin_amdgcn_cvt_pk_fp8_f32(v[0], v[1], 0, false);
      dw0 = (unsigned)__builtin_amdgcn_cvt_pk_fp8_f32(v[2], v[3], (int)dw0, true);
      unsigned dw1 = (unsigned)__builtin_amdgcn_cvt_pk_fp8_f32(v[4], v[5], 0, false);
      dw1 = (unsigned)__builtin_amdgcn_cvt_pk_fp8_f32(v[6], v[7], (int)dw1, true);
      unsigned dw2 = (unsigned)__builtin_amdgcn_cvt_pk_fp8_f32(v[8], v[9], 0, false);
      dw2 = (unsigned)__builtin_amdgcn_cvt_pk_fp8_f32(v[10], v[11], (int)dw2, true);
      unsigned dw3 = (unsigned)__builtin_amdgcn_cvt_pk_fp8_f32(v[12], v[13], 0, false);
      dw3 = (unsigned)__builtin_amdgcn_cvt_pk_fp8_f32(v[14], v[15], (int)dw3, true);
      unsigned* xw = xp1w + (size_t)row*64;
      xw[n]      = dw0;
      xw[16 + n] = dw1;
      xw[32 + n] = dw2;
      xw[48 + n] = dw3;
      float vE = acc[16][reg];
      if (n < 8) asrc[row*8 + n] = vE;
      else       adst[row*8 + (n - 8)] = vE;
    }
  }
}

// ---------------- CSR build (dst-sorted) ----------------
__global__ __launch_bounds__(256) void k_scan1(const int* __restrict__ deg, int* part, int* bsum){
  __shared__ int lds[256];
  const int t = threadIdx.x;
  const int base = blockIdx.x*1024;
  int v[4]; int s = 0;
  #pragma unroll
  for (int i = 0; i < 4; ++i){ int idx = base + t*4 + i; v[i] = (idx < NN) ? deg[idx] : 0; s += v[i]; }
  lds[t] = s; __syncthreads();
  for (int off = 1; off < 256; off <<= 1){
    int xx = (t >= off) ? lds[t-off] : 0;
    __syncthreads();
    lds[t] += xx;
    __syncthreads();
  }
  int excl = lds[t] - s;
  #pragma unroll
  for (int i = 0; i < 4; ++i){ int idx = base + t*4 + i; if (idx < NN) part[idx] = excl; excl += v[i]; }
  if (t == 255) bsum[blockIdx.x] = lds[255];
}
__global__ void k_scan2(const int* __restrict__ bsum, int* boff){
  const int l = threadIdx.x;   // 64 threads, lane i handles elements i and 64+i
  int a = (l      < 98) ? bsum[l]      : 0;
  int b = (64 + l < 98) ? bsum[64 + l] : 0;
  int sa = a, sb = b;
  #pragma unroll
  for (int off = 1; off < 64; off <<= 1){
    int ta = __shfl_up(sa, off, 64);
    int tb = __shfl_up(sb, off, 64);
    if (l >= off){ sa += ta; sb += tb; }
  }
  const int totalA = __shfl(sa, 63, 64);
  if (l      < 98) boff[l]      = sa - a;
  if (64 + l < 98) boff[64 + l] = totalA + sb - b;
}
__global__ __launch_bounds__(256) void k_scan3(const int* __restrict__ part, const int* __restrict__ boff,
                                               int* rowptr, int* cursor){
  int i = blockIdx.x*256 + threadIdx.x;
  if (i < NN){ int v = part[i] + boff[i >> 10]; rowptr[i] = v; cursor[i] = v; }
  if (i == 0) rowptr[NN] = NN + NE;
}
// XCD-partitioned fill: blocks dispatch round-robin over the 8 XCDs (bid&7); each esrc/cursor
// line is written by exactly one XCD's L2 (kills partial-line HBM write amplification).
__global__ __launch_bounds__(256) void k_fill(const int* __restrict__ ei, int* cursor, int* __restrict__ esrc){
  const int xcd = blockIdx.x & 7;
  const int base = (blockIdx.x >> 3) * FCHUNK;
  const int lo = xcd * (NN/8), hi = lo + (NN/8);
  const int end = (base + FCHUNK < NE + NN) ? (base + FCHUNK) : (NE + NN);
  for (int i = base + threadIdx.x; i < end; i += 256){
    int s, d;
    if (i < NE){ s = ei[i]; d = ei[NE + i]; } else { s = d = i - NE; }
    if (d >= lo && d < hi){
      int slot = atomicAdd(&cursor[d], 1);
      esrc[slot] = s;
    }
  }
}

// ---------------- K3: layer-1 aggregation ----------------
// Slot-major p layout: lane holds p for slot (lane&15) at heads hA=(lane>>4)*2 (pv0) and hA+1 (pv1).
template<int B>
static __device__ __forceinline__ void agg1_batch(
    const int j0, const int je, const int lane,
    const int* __restrict__ esrc, const float* __restrict__ asrc,
    const float adA, const float adB,
    const unsigned* __restrict__ xp1w,
    f2v& accLo, f2v& accHi, float& z0, float& z1)
{
  const int cnt = je - j0;                 // wave-uniform
  const int slot = lane & 15;
  const int hA = (lane >> 4) << 1;
  int idx = j0 + slot; idx = idx < je ? idx : je - 1;   // clamped, always valid
  const int sv = esrc[idx];                // lanes 0..15 hold slots 0..15
  float pv0 = 0.f, pv1 = 0.f;
  if (slot < cnt){
    f2v av = *(const f2v*)(asrc + (size_t)sv*8 + hA);
    pv0 = __expf(leaky(av.x + adA));
    pv1 = __expf(leaky(av.y + adB));
  }
  z0 += pv0; z1 += pv1;
  // phase 1: B unconditional row loads from clamped SGPR bases (padded slots repeat last row -> L1)
  unsigned u[B];
  #pragma unroll
  for (int e = 0; e < B; ++e){
    int s = __builtin_amdgcn_readlane(sv, e);
    u[e] = xp1w[(size_t)s*64 + lane];
  }
  __builtin_amdgcn_sched_barrier(0);   // pin: all loads issued before any FMA below
  // phase 2: decode + fma (p = 0 for padded slots -> garbage-free)
  const int pb = lane & 48;
  #pragma unroll
  for (int e = 0; e < B; ++e){
    const float pA = __shfl(pv0, pb | e, 64);
    const float pB = __shfl(pv1, pb | e, 64);
    f2v lo = __builtin_amdgcn_cvt_pk_f32_fp8((int)u[e], false);
    f2v hi = __builtin_amdgcn_cvt_pk_f32_fp8((int)u[e], true);
    accLo += (f2v){pA, pA} * lo;
    accHi += (f2v){pB, pB} * hi;
  }
}

__global__ __launch_bounds__(256) void k_agg1(const unsigned* __restrict__ xp1w,
    const float* __restrict__ asrc, const float* __restrict__ adst,
    const float* __restrict__ b1, const int* __restrict__ rowptr,
    const int* __restrict__ esrc, _Float16* __restrict__ h1)
{
  const int lane = threadIdx.x & 63;
  int n = __builtin_amdgcn_readfirstlane(blockIdx.x*4 + (threadIdx.x >> 6));
  const int hA = (lane >> 4) << 1;
  const f2v ad = *(const f2v*)(adst + (size_t)n*8 + hA);   // both heads' dst terms
  const int jb = rowptr[n], je = rowptr[n+1];
  const int cbase = (lane>>5)*128 + ((lane>>4)&1)*64 + (lane&15);
  const float bp0 = b1[cbase], bp1 = b1[cbase+16], bp2 = b1[cbase+32], bp3 = b1[cbase+48];
  f2v accLo = {0.f,0.f}, accHi = {0.f,0.f};
  float z0 = 0.f, z1 = 0.f;

  int j0 = jb;
  while (j0 < je){
    if (je - j0 > 8){
      agg1_batch<16>(j0, je, lane, esrc, asrc, ad.x, ad.y, xp1w, accLo, accHi, z0, z1);
      j0 += 16;
    } else {
      agg1_batch<8>(j0, je, lane, esrc, asrc, ad.x, ad.y, xp1w, accLo, accHi, z0, z1);
      j0 += 8;
    }
  }
  #pragma unroll
  for (int off = 1; off <= 8; off <<= 1){
    z0 += __shfl_xor(z0, off, 64);
    z1 += __shfl_xor(z1, off, 64);
  }
  const float invA = 1.f/(z0 + 1e-16f), invB = 1.f/(z1 + 1e-16f);
  h4 o = {(_Float16)fmaxf(accLo.x*invA + bp0, 0.f),
          (_Float16)fmaxf(accLo.y*invA + bp1, 0.f),
          (_Float16)fmaxf(accHi.x*invB + bp2, 0.f),
          (_Float16)fmaxf(accHi.y*invB + bp3, 0.f)};
  ((h4*)h1)[(size_t)n*64 + lane] = o;   // h1 inherits the permuted col order
}

// ---------------- K4: xp2 = h1 @ W2 via fp16 MFMA; attention dots via extra col tile ----------------
__global__ __launch_bounds__(256) void k_gemm2(const _Float16* __restrict__ h1,
    const _Float16* __restrict__ W2t, _Float16* __restrict__ xp2,
    float* __restrict__ asrc2, float* __restrict__ adst2)
{
  const int tid  = threadIdx.x;
  const int lane = tid & 63;
  const int w    = tid >> 6;
  const int n = lane & 15, quad = lane >> 4;
  const int r0 = blockIdx.x * 64 + w*16;

  f4v acc[4];
  #pragma unroll
  for (int ct = 0; ct < 4; ++ct) acc[ct] = (f4v){0.f,0.f,0.f,0.f};

  int rr = r0 + n; rr = rr < NN ? rr : NN-1;

  #pragma unroll
  for (int ks = 0; ks < 8; ++ks){
    h8 a = *(const h8*)(h1 + (size_t)rr*256 + ks*32 + quad*8);
    #pragma unroll
    for (int ct = 0; ct < 4; ++ct){
      h8 b = *(const h8*)(W2t + (size_t)(ct*16 + n)*256 + ks*32 + quad*8);
      acc[ct] = __builtin_amdgcn_mfma_f32_16x16x32_f16(a, b, acc[ct], 0, 0, 0);
    }
  }

  #pragma unroll
  for (int reg = 0; reg < 4; ++reg){
    const int row = r0 + quad*4 + reg;
    if (row < NN){
      float v0 = acc[0][reg], v1 = acc[1][reg], v2 = acc[2][reg], v3 = acc[3][reg];
      _Float16* xr = xp2 + (size_t)row*XPAD + n;
      xr[0]  = (_Float16)v0;
      xr[16] = (_Float16)v1;
      if (n < 8) xr[32] = (_Float16)v2;
      if (n == 0) asrc2[row] = v3;
      if (n == 1) adst2[row] = v3;
    }
  }
}

// ---------------- K5: layer-2 aggregation, 4 edges/wave (16-lane groups), b64 row loads ----------------
__global__ __launch_bounds__(256) void k_agg2(const _Float16* __restrict__ xp2,
    const float* __restrict__ asrc2, const float* __restrict__ adst2,
    const float* __restrict__ b2, const int* __restrict__ rowptr,
    const int* __restrict__ esrc, float* __restrict__ out)
{
  const int lane = threadIdx.x & 63;
  const int g = lane >> 4;          // edge sub-group 0..3
  const int t = lane & 15;          // channel quad: channels 4t..4t+3
  int n = __builtin_amdgcn_readfirstlane(blockIdx.x*4 + (threadIdx.x >> 6));
  const float ad = adst2[n];
  const int jb = rowptr[n], je = rowptr[n+1];
  f4v acc = {0.f,0.f,0.f,0.f};
  float zacc = 0.f;

  for (int j0 = jb; j0 < je; j0 += 16){
    const int cnt = je - j0;        // wave-uniform
    int idx = j0 + t; idx = idx < je ? idx : je - 1;   // clamped, always valid
    const int sv = esrc[idx];       // slot t (replicated across the 4 groups)
    const float pv = (t < cnt) ? __expf(leaky(asrc2[sv] + ad)) : 0.f;
    zacc += pv;
    // phase 1: 4 b64 loads, each covering 4 edges (one per group)
    h4 u[4];
    #pragma unroll
    for (int e4 = 0; e4 < 4; ++e4){
      int svg = __shfl(sv, e4*4 + g, 64);
      u[e4] = *(const h4*)(xp2 + (size_t)svg*XPAD + t*4);
    }
    __builtin_amdgcn_sched_barrier(0);   // pin: loads before FMA chain
    // phase 2: p broadcast + fma (p = 0 for padded slots -> garbage-free)
    #pragma unroll
    for (int e4 = 0; e4 < 4; ++e4){
      const float p = __shfl(pv, e4*4 + g, 64);
      acc.x += p*(float)u[e4].x;
      acc.y += p*(float)u[e4].y;
      acc.z += p*(float)u[e4].z;
      acc.w += p*(float)u[e4].w;
    }
  }
  // z over slots (groups identical)
  #pragma unroll
  for (int off = 1; off <= 8; off <<= 1) zacc += __shfl_xor(zacc, off, 64);
  // acc over the 4 edge groups (same channel quad t mixes only with itself)
  #pragma unroll
  for (int off = 16; off <= 32; off <<= 1){
    acc.x += __shfl_xor(acc.x, off, 64);
    acc.y += __shfl_xor(acc.y, off, 64);
    acc.z += __shfl_xor(acc.z, off, 64);
    acc.w += __shfl_xor(acc.w, off, 64);
  }
  const float inv = 1.f/(zacc + 1e-16f);
  const bool act = t < 10;          // 4t < OC=40
  float4 bv = act ? *(const float4*)(b2 + 4*t) : make_float4(0.f,0.f,0.f,0.f);
  float v0 = acc.x*inv + bv.x, v1 = acc.y*inv + bv.y;
  float v2 = acc.z*inv + bv.z, v3 = acc.w*inv + bv.w;
  float m = act ? fmaxf(fmaxf(v0,v1), fmaxf(v2,v3)) : -INFINITY;
  #pragma unroll
  for (int off = 1; off <= 8; off <<= 1) m = fmaxf(m, __shfl_xor(m, off, 64));
  float es = act ? (__expf(v0-m)+__expf(v1-m)+__expf(v2-m)+__expf(v3-m)) : 0.f;
  #pragma unroll
  for (int off = 1; off <= 8; off <<= 1) es += __shfl_xor(es, off, 64);
  if (lane < 10){                   // group 0, t<10: coalesced float4 stores
    float lse = m + __logf(es);
    float4 o = make_float4(v0-lse, v1-lse, v2-lse, v3-lse);
    *(float4*)(out + (size_t)n*OC + 4*t) = o;
  }
}

extern "C" void kernel_launch(void* const* d_in, const int* in_sizes, int n_in,
                              void* d_out, int out_size, void* d_ws, size_t ws_size,
                              hipStream_t stream)
{
  const float* x   = (const float*)d_in[0];
  const int*   ei  = (const int*)  d_in[1];
  const float* W1  = (const float*)d_in[2];
  const float* aS1 = (const float*)d_in[3];
  const float* aD1 = (const float*)d_in[4];
  const float* b1  = (const float*)d_in[5];
  const float* W2  = (const float*)d_in[6];
  const float* aS2 = (const float*)d_in[7];
  const float* aD2 = (const float*)d_in[8];
  const float* b2  = (const float*)d_in[9];
  float* out = (float*)d_out;

  char* wsp = (char*)d_ws;
  size_t off = 0;
  auto alloc = [&](size_t bytes){ void* p = wsp + off; off += (bytes + 255) & ~(size_t)255; return p; };
  unsigned* xp1w = (unsigned*)alloc((size_t)NN*C1);            // fp8, permuted, 64 dwords/row
  _Float16* h1  = (_Float16*)alloc((size_t)NN*C1*2);           // fp16, permuted cols
  float* as1  = (float*)alloc((size_t)NN*8*4);
  float* ad1  = (float*)alloc((size_t)NN*8*4);
  float* as2  = (float*)alloc((size_t)NN*4);
  float* ad2  = (float*)alloc((size_t)NN*4);
  int* deg    = (int*)alloc((size_t)NN*4);
  int* part   = (int*)alloc((size_t)NN*4);
  int* rowptr = (int*)alloc((size_t)(NN+1)*4);
  int* cursor = (int*)alloc((size_t)NN*4);
  int* bsum   = (int*)alloc(98*4);
  int* boff   = (int*)alloc(98*4);
  int* esrc   = (int*)alloc((size_t)(NN+NE)*4);
  _Float16* W1s = (_Float16*)alloc((size_t)272*128*2);   // swizzled B panel (256 + 16 dot cols)
  _Float16* W2t = (_Float16*)alloc((size_t)64*256*2);    // 48 cols + 16 (2 dot cols + zero pad)
  _Float16* xp2 = (_Float16*)alloc((size_t)NN*XPAD*2);   // 12.8 MB, 128B-aligned rows
  (void)ws_size; (void)in_sizes; (void)n_in; (void)out_size;

  const int fill_chunks = (NE + NN + FCHUNK - 1) / FCHUNK;   // 220
  const int deg_blocks  = (NE + 511) / 512;                  // 1563

  k_wt    <<<194 + (NN + 255)/256, 256, 0, stream>>>(W1, W2, aS1, aD1, aS2, aD2, W1s, W2t, deg);
  k_gemm1 <<<G1BLK + deg_blocks,   512, 0, stream>>>(x, W1s, xp1w, as1, ad1, ei, deg);
  k_scan1 <<<98,   256, 0, stream>>>(deg, part, bsum);
  k_scan2 <<<1,    64,  0, stream>>>(bsum, boff);
  k_scan3 <<<391,  256, 0, stream>>>(part, boff, rowptr, cursor);
  k_fill  <<<fill_chunks*8, 256, 0, stream>>>(ei, cursor, esrc);
  k_agg1  <<<25000,256, 0, stream>>>(xp1w, as1, ad1, b1, rowptr, esrc, h1);
  k_gemm2 <<<1563, 256, 0, stream>>>(h1, W2t, xp2, as2, ad2);
  k_agg2  <<<25000,256, 0, stream>>>(xp2, as2, ad2, b2, rowptr, esrc, out);
}

// Round 7
// 308.535 us; speedup vs baseline: 1.1525x; 1.0460x over previous
//
#include <hip/hip_runtime.h>
#include <math.h>

#define NN 100000
#define NE 800000
#define C1 256   // HEADS*HID
#define OC 40
#define XPAD 64  // padded xp2 row stride (fp16) = 128 B = 1 cacheline
#define NEG 0.2f
#define FCHUNK 4096
#define G1BLK 782    // gemm1 compute blocks (512 thr, 128 rows); blocks beyond run deg_count

typedef _Float16 h4 __attribute__((ext_vector_type(4)));
typedef _Float16 h8 __attribute__((ext_vector_type(8)));
typedef float f4v __attribute__((ext_vector_type(4)));
typedef float f2v __attribute__((ext_vector_type(2)));

static __device__ __forceinline__ float leaky(float v){ return v > 0.f ? v : NEG*v; }

static __device__ __forceinline__ h8 mk8(float4 a, float4 b){
  h8 r = {(_Float16)a.x,(_Float16)a.y,(_Float16)a.z,(_Float16)a.w,
          (_Float16)b.x,(_Float16)b.y,(_Float16)b.z,(_Float16)b.w};
  return r;
}

static __device__ __forceinline__ void gload_lds16h(const _Float16* g, _Float16* l){
  __builtin_amdgcn_global_load_lds((const __attribute__((address_space(1))) void*)g,
                                   (__attribute__((address_space(3))) void*)l, 16, 0, 0);
}

// Permuted xp1/h1 row layout: storage element e = 4*l + j (l = dword/lane 0..63, j = byte 0..3)
// holds logical col pcol(l,j) = (l>>5)*128 + ((l>>4)&1)*64 + 16*j + (l&15).
//
// W1s layout (swizzled B panel, 272 cols x 128 k, fp16): col c's 256B row is split into 16
// segments of 16B (segment s = k>>3); segment s is STORED at slot s^(c&15). gemm1 stages this
// linearly into LDS (global_load_lds can't scatter) and applies the same XOR on ds_read ->
// bank-conflict-free b128 reads (rule: swizzle both sides or neither).

// ---------------- W1s/W2t transforms + deg init (fused: blocks 194.. init deg) ----------------
__global__ __launch_bounds__(256) void k_wt(const float* __restrict__ W1, const float* __restrict__ W2,
                                            const float* __restrict__ aS1, const float* __restrict__ aD1,
                                            const float* __restrict__ aS2, const float* __restrict__ aD2,
                                            _Float16* __restrict__ W1s, _Float16* __restrict__ W2t,
                                            int* __restrict__ deg){
  int b = blockIdx.x;
  if (b < 128){
    int k = b, c = threadIdx.x;
    W1s[(size_t)c*128 + (((k>>3) ^ (c&15))<<3) + (k&7)] = (_Float16)W1[k*256 + c];
  } else if (b < 176){
    int nb = b - 128;            // 0..47 (pad 40->48 with zeros)
    int e = threadIdx.x;         // storage index 0..255
    int l = e >> 2, j = e & 3;
    int k = (l>>5)*128 + ((l>>4)&1)*64 + j*16 + (l&15);   // logical k of storage slot e
    float v = (nb < OC) ? W2[(size_t)k*OC + nb] : 0.f;
    W2t[(size_t)nb*256 + e] = (_Float16)v;
  } else if (b < 178){
    int b2 = b - 176;            // 0 = src heads, 1 = dst heads
    int h  = threadIdx.x >> 5;   // 0..7
    int kb = (threadIdx.x & 31) * 4;
    const float* att = b2 ? aD1 : aS1;
    const int c = 256 + b2*8 + h;
    #pragma unroll
    for (int kk = 0; kk < 4; ++kk){
      int k = kb + kk;
      float s = 0.f;
      for (int cc = 0; cc < 32; ++cc) s += W1[k*256 + h*32 + cc] * att[h*32 + cc];
      W1s[(size_t)c*128 + (((k>>3) ^ (c&15))<<3) + (k&7)] = (_Float16)s;
    }
  } else if (b < 194){
    int j = b - 178;             // 0..15 -> W2t col 48+j (j=0 src dot, j=1 dst dot, rest zero)
    int e = threadIdx.x;
    int l = e >> 2, jj = e & 3;
    int k = (l>>5)*128 + ((l>>4)&1)*64 + jj*16 + (l&15);
    float v = 0.f;
    if (j == 0){ for (int c = 0; c < OC; ++c) v += W2[(size_t)k*OC + c] * aS2[c]; }
    else if (j == 1){ for (int c = 0; c < OC; ++c) v += W2[(size_t)k*OC + c] * aD2[c]; }
    W2t[(size_t)(48 + j)*256 + e] = (_Float16)v;
  } else {
    int i = (b - 194)*256 + threadIdx.x;
    if (i < NN) deg[i] = 1;      // self-loop slot reserved
  }
}

// ---------------- K1: xp1 = x @ W1 via fp16 MFMA, full B panel in LDS ----------------
__global__ __launch_bounds__(512, 4) void k_gemm1(const float* __restrict__ x,
    const _Float16* __restrict__ W1s, unsigned* __restrict__ xp1w,
    float* __restrict__ asrc, float* __restrict__ adst,
    const int* __restrict__ ei, int* __restrict__ deg)
{
  __shared__ _Float16 bs[272*128];   // 69,632 B swizzled B panel
  if (blockIdx.x >= G1BLK){
    // deg_count rides in gemm1's latency bubbles (independent work, co-scheduled)
    int i = (blockIdx.x - G1BLK)*512 + threadIdx.x;
    if (i < NE) atomicAdd(&deg[ei[NE + i]], 1);
    return;
  }
  const int tid  = threadIdx.x;
  const int lane = tid & 63;
  const int w    = tid >> 6;          // 0..7
  const int n = lane & 15, quad = lane >> 4;
  const int r0 = blockIdx.x * 128 + w*16;

  // stage the whole swizzled panel linearly: 4352 x 16B segments
  #pragma unroll
  for (int it = 0; it < 8; ++it){
    int idx = it*512 + tid;
    gload_lds16h(W1s + (size_t)idx*8, bs + (size_t)(it*512 + w*64)*8);
  }
  if (w < 4){
    int idx = 4096 + w*64 + lane;
    gload_lds16h(W1s + (size_t)idx*8, bs + (size_t)(4096 + w*64)*8);
  }

  // issue all 8 A-loads up front (K=128 for this wave's 16 rows)
  int ra = r0 + n; ra = ra < NN ? ra : NN-1;
  const float* xr = x + (size_t)ra*128 + quad*8;
  float4 fa[4][2];
  #pragma unroll
  for (int ks = 0; ks < 4; ++ks){
    fa[ks][0] = *(const float4*)(xr + ks*32);
    fa[ks][1] = *(const float4*)(xr + ks*32 + 4);
  }

  __syncthreads();   // drains vmcnt (global_load_lds + A loads)

  f4v acc[17];
  #pragma unroll
  for (int ct = 0; ct < 17; ++ct) acc[ct] = (f4v){0.f,0.f,0.f,0.f};

  #pragma unroll
  for (int ks = 0; ks < 4; ++ks){
    h8 a = mk8(fa[ks][0], fa[ks][1]);
    #pragma unroll
    for (int ct = 0; ct < 17; ++ct){
      const int col = ct*16 + n;                     // ct=16 -> attention-dot cols 256+n
      h8 b = *((const h8*)bs + (size_t)col*16 + (((ks*4 + quad) ^ n)));
      acc[ct] = __builtin_amdgcn_mfma_f32_16x16x32_f16(a, b, acc[ct], 0, 0, 0);
    }
  }

  #pragma unroll
  for (int reg = 0; reg < 4; ++reg){
    const int row = r0 + quad*4 + reg;
    if (row < NN){
      float v[16];
      #pragma unroll
      for (int ct = 0; ct < 16; ++ct) v[ct] = acc[ct][reg];
      unsigned dw0 = (unsigned)__builtin_amdgcn_cvt_pk_fp8_f32(v[0], v[1], 0, false);
      dw0 = (unsigned)__builtin_amdgcn_cvt_pk_fp8_f32(v[2], v[3], (int)dw0, true);
      unsigned dw1 = (unsigned)__builtin_amdgcn_cvt_pk_fp8_f32(v[4], v[5], 0, false);
      dw1 = (unsigned)__builtin_amdgcn_cvt_pk_fp8_f32(v[6], v[7], (int)dw1, true);
      unsigned dw2 = (unsigned)__builtin_amdgcn_cvt_pk_fp8_f32(v[8], v[9], 0, false);
      dw2 = (unsigned)__builtin_amdgcn_cvt_pk_fp8_f32(v[10], v[11], (int)dw2, true);
      unsigned dw3 = (unsigned)__builtin_amdgcn_cvt_pk_fp8_f32(v[12], v[13], 0, false);
      dw3 = (unsigned)__builtin_amdgcn_cvt_pk_fp8_f32(v[14], v[15], (int)dw3, true);
      unsigned* xw = xp1w + (size_t)row*64;
      xw[n]      = dw0;
      xw[16 + n] = dw1;
      xw[32 + n] = dw2;
      xw[48 + n] = dw3;
      float vE = acc[16][reg];
      if (n < 8) asrc[row*8 + n] = vE;
      else       adst[row*8 + (n - 8)] = vE;
    }
  }
}

// ---------------- CSR build (dst-sorted) ----------------
__global__ __launch_bounds__(256) void k_scan1(const int* __restrict__ deg, int* part, int* bsum){
  __shared__ int lds[256];
  const int t = threadIdx.x;
  const int base = blockIdx.x*1024;
  int v[4]; int s = 0;
  #pragma unroll
  for (int i = 0; i < 4; ++i){ int idx = base + t*4 + i; v[i] = (idx < NN) ? deg[idx] : 0; s += v[i]; }
  lds[t] = s; __syncthreads();
  for (int off = 1; off < 256; off <<= 1){
    int xx = (t >= off) ? lds[t-off] : 0;
    __syncthreads();
    lds[t] += xx;
    __syncthreads();
  }
  int excl = lds[t] - s;
  #pragma unroll
  for (int i = 0; i < 4; ++i){ int idx = base + t*4 + i; if (idx < NN) part[idx] = excl; excl += v[i]; }
  if (t == 255) bsum[blockIdx.x] = lds[255];
}
__global__ void k_scan2(const int* __restrict__ bsum, int* boff){
  const int l = threadIdx.x;   // 64 threads, lane i handles elements i and 64+i
  int a = (l      < 98) ? bsum[l]      : 0;
  int b = (64 + l < 98) ? bsum[64 + l] : 0;
  int sa = a, sb = b;
  #pragma unroll
  for (int off = 1; off < 64; off <<= 1){
    int ta = __shfl_up(sa, off, 64);
    int tb = __shfl_up(sb, off, 64);
    if (l >= off){ sa += ta; sb += tb; }
  }
  const int totalA = __shfl(sa, 63, 64);
  if (l      < 98) boff[l]      = sa - a;
  if (64 + l < 98) boff[64 + l] = totalA + sb - b;
}
__global__ __launch_bounds__(256) void k_scan3(const int* __restrict__ part, const int* __restrict__ boff,
                                               int* rowptr, int* cursor){
  int i = blockIdx.x*256 + threadIdx.x;
  if (i < NN){ int v = part[i] + boff[i >> 10]; rowptr[i] = v; cursor[i] = v; }
  if (i == 0) rowptr[NN] = NN + NE;
}
// XCD-partitioned fill: blocks dispatch round-robin over the 8 XCDs (bid&7); each esrc/cursor
// line is written by exactly one XCD's L2 (kills partial-line HBM write amplification).
__global__ __launch_bounds__(256) void k_fill(const int* __restrict__ ei, int* cursor, int* __restrict__ esrc){
  const int xcd = blockIdx.x & 7;
  const int base = (blockIdx.x >> 3) * FCHUNK;
  const int lo = xcd * (NN/8), hi = lo + (NN/8);
  const int end = (base + FCHUNK < NE + NN) ? (base + FCHUNK) : (NE + NN);
  for (int i = base + threadIdx.x; i < end; i += 256){
    int s, d;
    if (i < NE){ s = ei[i]; d = ei[NE + i]; } else { s = d = i - NE; }
    if (d >= lo && d < hi){
      int slot = atomicAdd(&cursor[d], 1);
      esrc[slot] = s;
    }
  }
}

// ---------------- K3: layer-1 aggregation FUSED with layer-2 GEMM ----------------
// 1024 thr / 16 waves / 16 nodes per block. Each wave aggregates one node (identical logic to the
// standalone agg1), deposits its finished 256-ch h1 row in LDS (stride 264 fp16 -> bank-stride 4,
// 2-way = free), then after one barrier waves 0..3 run the 16x64 @ 256 MFMA tile (W2t L2-hot)
// and emit xp2 + attention dots. h1 NEVER touches HBM (-50 MB write, -50 MB read, -1 launch).
template<int B>
static __device__ __forceinline__ void agg1_batch(
    const int j0, const int je, const int lane,
    const int* __restrict__ esrc, const float* __restrict__ asrc,
    const float adA, const float adB,
    const unsigned* __restrict__ xp1w,
    f2v& accLo, f2v& accHi, float& z0, float& z1)
{
  const int cnt = je - j0;                 // wave-uniform
  const int slot = lane & 15;
  const int hA = (lane >> 4) << 1;
  int idx = j0 + slot; idx = idx < je ? idx : je - 1;   // clamped, always valid
  const int sv = esrc[idx];                // lanes 0..15 hold slots 0..15
  float pv0 = 0.f, pv1 = 0.f;
  if (slot < cnt){
    f2v av = *(const f2v*)(asrc + (size_t)sv*8 + hA);
    pv0 = __expf(leaky(av.x + adA));
    pv1 = __expf(leaky(av.y + adB));
  }
  z0 += pv0; z1 += pv1;
  // phase 1: B unconditional row loads from clamped SGPR bases (padded slots repeat last row -> L1)
  unsigned u[B];
  #pragma unroll
  for (int e = 0; e < B; ++e){
    int s = __builtin_amdgcn_readlane(sv, e);
    u[e] = xp1w[(size_t)s*64 + lane];
  }
  __builtin_amdgcn_sched_barrier(0);   // pin: all loads issued before any FMA below
  // phase 2: decode + fma (p = 0 for padded slots -> garbage-free)
  const int pb = lane & 48;
  #pragma unroll
  for (int e = 0; e < B; ++e){
    const float pA = __shfl(pv0, pb | e, 64);
    const float pB = __shfl(pv1, pb | e, 64);
    f2v lo = __builtin_amdgcn_cvt_pk_f32_fp8((int)u[e], false);
    f2v hi = __builtin_amdgcn_cvt_pk_f32_fp8((int)u[e], true);
    accLo += (f2v){pA, pA} * lo;
    accHi += (f2v){pB, pB} * hi;
  }
}

__global__ __launch_bounds__(1024) void k_agg1(const unsigned* __restrict__ xp1w,
    const float* __restrict__ asrc, const float* __restrict__ adst,
    const float* __restrict__ b1, const int* __restrict__ rowptr,
    const int* __restrict__ esrc, const _Float16* __restrict__ W2t,
    _Float16* __restrict__ xp2, float* __restrict__ asrc2, float* __restrict__ adst2)
{
  __shared__ _Float16 hs[16*264];    // 16 h1 rows, stride 264 fp16 (8448 B)
  const int lane = threadIdx.x & 63;
  const int w = threadIdx.x >> 6;    // 0..15, one node per wave
  int n = __builtin_amdgcn_readfirstlane(blockIdx.x*16 + w);
  const int hA = (lane >> 4) << 1;
  const f2v ad = *(const f2v*)(adst + (size_t)n*8 + hA);   // both heads' dst terms
  const int jb = rowptr[n], je = rowptr[n+1];
  const int cbase = (lane>>5)*128 + ((lane>>4)&1)*64 + (lane&15);
  const float bp0 = b1[cbase], bp1 = b1[cbase+16], bp2 = b1[cbase+32], bp3 = b1[cbase+48];
  f2v accLo = {0.f,0.f}, accHi = {0.f,0.f};
  float z0 = 0.f, z1 = 0.f;

  int j0 = jb;
  while (j0 < je){
    if (je - j0 > 8){
      agg1_batch<16>(j0, je, lane, esrc, asrc, ad.x, ad.y, xp1w, accLo, accHi, z0, z1);
      j0 += 16;
    } else {
      agg1_batch<8>(j0, je, lane, esrc, asrc, ad.x, ad.y, xp1w, accLo, accHi, z0, z1);
      j0 += 8;
    }
  }
  #pragma unroll
  for (int off = 1; off <= 8; off <<= 1){
    z0 += __shfl_xor(z0, off, 64);
    z1 += __shfl_xor(z1, off, 64);
  }
  const float invA = 1.f/(z0 + 1e-16f), invB = 1.f/(z1 + 1e-16f);
  h4 o = {(_Float16)fmaxf(accLo.x*invA + bp0, 0.f),
          (_Float16)fmaxf(accLo.y*invA + bp1, 0.f),
          (_Float16)fmaxf(accHi.x*invB + bp2, 0.f),
          (_Float16)fmaxf(accHi.y*invB + bp3, 0.f)};
  ((h4*)(hs + (size_t)w*264))[lane] = o;   // h1 row -> LDS (permuted col order preserved)

  __syncthreads();

  if (w < 4){
    // 16x16 tile of xp2 = h1_block @ W2t, ct = w (cols 16w..16w+15); identical math to old gemm2
    const int nq = lane & 15, quad = lane >> 4;
    f4v acc = (f4v){0.f,0.f,0.f,0.f};
    #pragma unroll
    for (int ks = 0; ks < 8; ++ks){
      h8 a = *(const h8*)(hs + (size_t)nq*264 + ks*32 + quad*8);
      h8 b = *(const h8*)(W2t + (size_t)(w*16 + nq)*256 + ks*32 + quad*8);
      acc = __builtin_amdgcn_mfma_f32_16x16x32_f16(a, b, acc, 0, 0, 0);
    }
    const int nb = __builtin_amdgcn_readfirstlane(blockIdx.x*16);
    #pragma unroll
    for (int reg = 0; reg < 4; ++reg){
      const int row = nb + quad*4 + reg;     // grid exact: always < NN
      float v = acc[reg];
      _Float16* xr = xp2 + (size_t)row*XPAD;
      if (w == 0)      xr[nq]      = (_Float16)v;
      else if (w == 1) xr[16 + nq] = (_Float16)v;
      else if (w == 2){ if (nq < 8) xr[32 + nq] = (_Float16)v; }
      else { if (nq == 0) asrc2[row] = v; else if (nq == 1) adst2[row] = v; }
    }
  }
}

// ---------------- K5: layer-2 aggregation, 4 edges/wave (16-lane groups), b64 row loads ----------------
__global__ __launch_bounds__(256) void k_agg2(const _Float16* __restrict__ xp2,
    const float* __restrict__ asrc2, const float* __restrict__ adst2,
    const float* __restrict__ b2, const int* __restrict__ rowptr,
    const int* __restrict__ esrc, float* __restrict__ out)
{
  const int lane = threadIdx.x & 63;
  const int g = lane >> 4;          // edge sub-group 0..3
  const int t = lane & 15;          // channel quad: channels 4t..4t+3
  int n = __builtin_amdgcn_readfirstlane(blockIdx.x*4 + (threadIdx.x >> 6));
  const float ad = adst2[n];
  const int jb = rowptr[n], je = rowptr[n+1];
  f4v acc = {0.f,0.f,0.f,0.f};
  float zacc = 0.f;

  for (int j0 = jb; j0 < je; j0 += 16){
    const int cnt = je - j0;        // wave-uniform
    int idx = j0 + t; idx = idx < je ? idx : je - 1;   // clamped, always valid
    const int sv = esrc[idx];       // slot t (replicated across the 4 groups)
    const float pv = (t < cnt) ? __expf(leaky(asrc2[sv] + ad)) : 0.f;
    zacc += pv;
    // phase 1: 4 b64 loads, each covering 4 edges (one per group)
    h4 u[4];
    #pragma unroll
    for (int e4 = 0; e4 < 4; ++e4){
      int svg = __shfl(sv, e4*4 + g, 64);
      u[e4] = *(const h4*)(xp2 + (size_t)svg*XPAD + t*4);
    }
    __builtin_amdgcn_sched_barrier(0);   // pin: loads before FMA chain
    // phase 2: p broadcast + fma (p = 0 for padded slots -> garbage-free)
    #pragma unroll
    for (int e4 = 0; e4 < 4; ++e4){
      const float p = __shfl(pv, e4*4 + g, 64);
      acc.x += p*(float)u[e4].x;
      acc.y += p*(float)u[e4].y;
      acc.z += p*(float)u[e4].z;
      acc.w += p*(float)u[e4].w;
    }
  }
  // z over slots (groups identical)
  #pragma unroll
  for (int off = 1; off <= 8; off <<= 1) zacc += __shfl_xor(zacc, off, 64);
  // acc over the 4 edge groups (same channel quad t mixes only with itself)
  #pragma unroll
  for (int off = 16; off <= 32; off <<= 1){
    acc.x += __shfl_xor(acc.x, off, 64);
    acc.y += __shfl_xor(acc.y, off, 64);
    acc.z += __shfl_xor(acc.z, off, 64);
    acc.w += __shfl_xor(acc.w, off, 64);
  }
  const float inv = 1.f/(zacc + 1e-16f);
  const bool act = t < 10;          // 4t < OC=40
  float4 bv = act ? *(const float4*)(b2 + 4*t) : make_float4(0.f,0.f,0.f,0.f);
  float v0 = acc.x*inv + bv.x, v1 = acc.y*inv + bv.y;
  float v2 = acc.z*inv + bv.z, v3 = acc.w*inv + bv.w;
  float m = act ? fmaxf(fmaxf(v0,v1), fmaxf(v2,v3)) : -INFINITY;
  #pragma unroll
  for (int off = 1; off <= 8; off <<= 1) m = fmaxf(m, __shfl_xor(m, off, 64));
  float es = act ? (__expf(v0-m)+__expf(v1-m)+__expf(v2-m)+__expf(v3-m)) : 0.f;
  #pragma unroll
  for (int off = 1; off <= 8; off <<= 1) es += __shfl_xor(es, off, 64);
  if (lane < 10){                   // group 0, t<10: coalesced float4 stores
    float lse = m + __logf(es);
    float4 o = make_float4(v0-lse, v1-lse, v2-lse, v3-lse);
    *(float4*)(out + (size_t)n*OC + 4*t) = o;
  }
}

extern "C" void kernel_launch(void* const* d_in, const int* in_sizes, int n_in,
                              void* d_out, int out_size, void* d_ws, size_t ws_size,
                              hipStream_t stream)
{
  const float* x   = (const float*)d_in[0];
  const int*   ei  = (const int*)  d_in[1];
  const float* W1  = (const float*)d_in[2];
  const float* aS1 = (const float*)d_in[3];
  const float* aD1 = (const float*)d_in[4];
  const float* b1  = (const float*)d_in[5];
  const float* W2  = (const float*)d_in[6];
  const float* aS2 = (const float*)d_in[7];
  const float* aD2 = (const float*)d_in[8];
  const float* b2  = (const float*)d_in[9];
  float* out = (float*)d_out;

  char* wsp = (char*)d_ws;
  size_t off = 0;
  auto alloc = [&](size_t bytes){ void* p = wsp + off; off += (bytes + 255) & ~(size_t)255; return p; };
  unsigned* xp1w = (unsigned*)alloc((size_t)NN*C1);            // fp8, permuted, 64 dwords/row
  float* as1  = (float*)alloc((size_t)NN*8*4);
  float* ad1  = (float*)alloc((size_t)NN*8*4);
  float* as2  = (float*)alloc((size_t)NN*4);
  float* ad2  = (float*)alloc((size_t)NN*4);
  int* deg    = (int*)alloc((size_t)NN*4);
  int* part   = (int*)alloc((size_t)NN*4);
  int* rowptr = (int*)alloc((size_t)(NN+1)*4);
  int* cursor = (int*)alloc((size_t)NN*4);
  int* bsum   = (int*)alloc(98*4);
  int* boff   = (int*)alloc(98*4);
  int* esrc   = (int*)alloc((size_t)(NN+NE)*4);
  _Float16* W1s = (_Float16*)alloc((size_t)272*128*2);   // swizzled B panel (256 + 16 dot cols)
  _Float16* W2t = (_Float16*)alloc((size_t)64*256*2);    // 48 cols + 16 (2 dot cols + zero pad)
  _Float16* xp2 = (_Float16*)alloc((size_t)NN*XPAD*2);   // 12.8 MB, 128B-aligned rows
  (void)ws_size; (void)in_sizes; (void)n_in; (void)out_size;

  const int fill_chunks = (NE + NN + FCHUNK - 1) / FCHUNK;   // 220
  const int deg_blocks  = (NE + 511) / 512;                  // 1563

  k_wt    <<<194 + (NN + 255)/256, 256, 0, stream>>>(W1, W2, aS1, aD1, aS2, aD2, W1s, W2t, deg);
  k_gemm1 <<<G1BLK + deg_blocks,   512, 0, stream>>>(x, W1s, xp1w, as1, ad1, ei, deg);
  k_scan1 <<<98,   256, 0, stream>>>(deg, part, bsum);
  k_scan2 <<<1,    64,  0, stream>>>(bsum, boff);
  k_scan3 <<<391,  256, 0, stream>>>(part, boff, rowptr, cursor);
  k_fill  <<<fill_chunks*8, 256, 0, stream>>>(ei, cursor, esrc);
  k_agg1  <<<6250, 1024, 0, stream>>>(xp1w, as1, ad1, b1, rowptr, esrc, W2t, xp2, as2, ad2);
  k_agg2  <<<25000,256, 0, stream>>>(xp2, as2, ad2, b2, rowptr, esrc, out);
}